// Round 1
// baseline (557.543 us; speedup 1.0000x reference)
//
#include <hip/hip_runtime.h>

// out[n, f, h] = x[n, f] * W[f, h] + b[f, h]
// x: [16384, 128] f32, W: [128, 64] f32, b: [128, 64] f32
// out: [16384, 128, 64] f32  (h contiguous)
//
// Memory-bound: 512 MiB store + 8 MiB x read. One thread per float4 of
// output -> 16 threads per (n,f) pair, 16 B/lane coalesced stores.

#define BATCH 16384
#define NFEAT 128
#define HID 64
#define H4 (HID / 4)                      // 16 float4 per (n,f)
#define TOTAL_VEC4 (BATCH * NFEAT * H4)   // 2^25 float4 stores

__global__ __launch_bounds__(256) void ifl_kernel(
    const float* __restrict__ x,
    const float* __restrict__ W,
    const float* __restrict__ b,
    float* __restrict__ out) {
    unsigned int t = blockIdx.x * blockDim.x + threadIdx.x;  // < 2^25

    unsigned int h4 = t & (H4 - 1);       // which float4 along h
    unsigned int nf = t >> 4;             // (n*128 + f)
    unsigned int f  = nf & (NFEAT - 1);

    float xv = x[nf];                     // nf == n*NFEAT + f, x is [n][f]
    float4 w4 = ((const float4*)W)[f * H4 + h4];
    float4 b4 = ((const float4*)b)[f * H4 + h4];

    float4 o;
    o.x = fmaf(xv, w4.x, b4.x);
    o.y = fmaf(xv, w4.y, b4.y);
    o.z = fmaf(xv, w4.z, b4.z);
    o.w = fmaf(xv, w4.w, b4.w);

    ((float4*)out)[t] = o;
}

extern "C" void kernel_launch(void* const* d_in, const int* in_sizes, int n_in,
                              void* d_out, int out_size, void* d_ws, size_t ws_size,
                              hipStream_t stream) {
    const float* x = (const float*)d_in[0];
    const float* W = (const float*)d_in[1];
    const float* b = (const float*)d_in[2];
    float* out = (float*)d_out;

    const int block = 256;
    const int grid = TOTAL_VEC4 / block;  // 131072 blocks
    ifl_kernel<<<grid, block, 0, stream>>>(x, W, b, out);
}

// Round 2
// 546.676 us; speedup vs baseline: 1.0199x; 1.0199x over previous
//
#include <hip/hip_runtime.h>

// out[n, f, h] = x[n, f] * W[f, h] + b[f, h]
// x: [16384, 128] f32, W/b: [128, 64] f32, out: [16384, 128, 64] f32.
//
// Write-BW-bound (512 MiB store). Strategy:
//  - W+b (64 KB) staged in LDS once per block -> kills 1 GiB L1/L2 read
//    amplification from per-wave reloads.
//  - Non-temporal loads/stores: the 512 MiB streaming write no longer
//    thrashes L2, and x/W/b are each read exactly once from global.
//  - 1024-thread blocks, 64 KB LDS -> 2 blocks/CU co-resident = 32 waves/CU.
//  - Each block owns a contiguous 64 Ki-float4 (1 MiB) output chunk,
//    iterating with stride 1024 so every wave stores 1 KB coalesced.
//
// Index trick: flat float4 index idx = ((n*128 + f)<<4) | h4, so the W/b
// LDS offset (f*16 + h4) is just idx & 2047, and the x index is idx >> 4.

typedef float f4 __attribute__((ext_vector_type(4)));

#define BATCH 16384
#define NFEAT 128
#define H4 16
#define TOTAL_VEC4 (BATCH * NFEAT * H4)      // 33,554,432 float4
#define BLOCK 1024
#define GRID 512
#define ITERS (TOTAL_VEC4 / (BLOCK * GRID))  // 64

__global__ __launch_bounds__(BLOCK) void ifl_kernel(
    const float* __restrict__ x,
    const f4* __restrict__ W4,
    const f4* __restrict__ B4,
    f4* __restrict__ out) {
    __shared__ f4 sW[NFEAT * H4];   // 2048 * 16 B = 32 KB
    __shared__ f4 sB[NFEAT * H4];   // 32 KB

    const unsigned t = threadIdx.x;
    sW[t]        = __builtin_nontemporal_load(&W4[t]);
    sW[t + 1024] = __builtin_nontemporal_load(&W4[t + 1024]);
    sB[t]        = __builtin_nontemporal_load(&B4[t]);
    sB[t + 1024] = __builtin_nontemporal_load(&B4[t + 1024]);
    __syncthreads();

    const unsigned base = blockIdx.x * (BLOCK * ITERS) + t;
#pragma unroll 4
    for (int i = 0; i < ITERS; ++i) {
        unsigned idx = base + i * BLOCK;
        unsigned wb  = idx & (NFEAT * H4 - 1);   // f*16 + h4
        float xv = __builtin_nontemporal_load(&x[idx >> 4]);
        f4 w = sW[wb];
        f4 bb = sB[wb];
        f4 o;
        o.x = fmaf(xv, w.x, bb.x);
        o.y = fmaf(xv, w.y, bb.y);
        o.z = fmaf(xv, w.z, bb.z);
        o.w = fmaf(xv, w.w, bb.w);
        __builtin_nontemporal_store(o, &out[idx]);
    }
}

extern "C" void kernel_launch(void* const* d_in, const int* in_sizes, int n_in,
                              void* d_out, int out_size, void* d_ws, size_t ws_size,
                              hipStream_t stream) {
    const float* x = (const float*)d_in[0];
    const f4* W4 = (const f4*)d_in[1];
    const f4* B4 = (const f4*)d_in[2];
    f4* out = (f4*)d_out;

    ifl_kernel<<<GRID, BLOCK, 0, stream>>>(x, W4, B4, out);
}